// Round 9
// baseline (442.991 us; speedup 1.0000x reference)
//
#include <hip/hip_runtime.h>

// ---------------- problem constants ----------------
#define N_WORDS 16384
#define MAXL    16
#define VOCABSZ 128
#define EMBD    64
#define HID     256
#define GATES   1024        // 4*HID
#define KTOT    320         // HID + EMBD (x folded into K)
#define AROW    328         // A row stride in shorts (656 B = 640 + 16 pad)
#define M_TILE  32          // words per workgroup (2 blocks/CU)
#define NT      512         // word tiles (N_WORDS / M_TILE)

typedef __attribute__((ext_vector_type(8))) short bf16x8;  // 8 bf16 = 4 VGPRs
typedef __attribute__((ext_vector_type(4))) float f32x4;
typedef __attribute__((ext_vector_type(2))) float f32x2;
typedef __attribute__((ext_vector_type(4))) int   i32x4;

// ---------------- workspace layout (bytes) ----------------
// wsw : swizzled weights, A-fragment order: [dir][R 0..63][kk 0..9][lane 0..63][8 bf16]
#define OFF_WSW   0ul          // 2*64*10*64*16 = 1310720
#define OFF_EMB   1310720ul    // 128*64 bf16 = 16384
#define OFF_BIAS  1327104ul    // 2*1024 f32 = 8192 (interleaved unit-major: [4*unit+type])
#define OFF_SORT  1335296ul    // 16384 ints = 65536
// cell state lives in LDS -- no global c buffer

__device__ inline short tobf(float f) {           // fp32 -> bf16 RNE
  unsigned u = __float_as_uint(f);
  unsigned r = (u + 0x7fffu + ((u >> 16) & 1u)) >> 16;
  return (short)r;
}
// raw transcendental units via inline asm
__device__ inline float aexp2(float x) { float r; asm("v_exp_f32 %0, %1" : "=v"(r) : "v"(x)); return r; }
__device__ inline float arcp(float x)  { float r; asm("v_rcp_f32 %0, %1" : "=v"(r) : "v"(x)); return r; }
__device__ inline float fsig(float x)   { return arcp(1.0f + aexp2(x * -1.4426950408889634f)); }
__device__ inline float ftanhf(float x) { return 1.0f - 2.0f * arcp(1.0f + aexp2(x * 2.8853900817779268f)); }

// ---------------- fused prep: weight swizzle + emb/bias + length-sort (1 launch) --
__global__ void prep_all(const float* __restrict__ Wihf, const float* __restrict__ Whhf,
                         const float* __restrict__ Wihb, const float* __restrict__ Whhb,
                         const float* __restrict__ emb,
                         const float* __restrict__ bihf, const float* __restrict__ bhhf,
                         const float* __restrict__ bihb, const float* __restrict__ bhhb,
                         const int* __restrict__ lengths,
                         short* __restrict__ wsw, short* __restrict__ embw,
                         float* __restrict__ biasg, int* __restrict__ sorted) {
  __shared__ int hist[16], base[16], cnt[16];
  int blk = blockIdx.x;
  if (blk < 320) {
    int id = blk * 256 + threadIdx.x;            // 2*64*10*64 = 81920
    int d    = id / 40960;
    int r    = id % 40960;
    int R    = r / 640;
    int r2   = r % 640;
    int kk   = r2 / 64;
    int lane = r2 % 64;
    int m    = lane & 15;
    int unit = R * 4 + (m >> 2);
    int ty   = m & 3;
    int g    = ty * 256 + unit;
    int kb   = kk * 32 + (lane >> 4) * 8;
    const float* Wih = d ? Wihb : Wihf;
    const float* Whh = d ? Whhb : Whhf;
    bf16x8 v;
#pragma unroll
    for (int j = 0; j < 8; ++j) {
      int k = kb + j;
      float f = (k < HID) ? Whh[g * HID + k] : Wih[g * EMBD + (k - HID)];
      v[j] = tobf(f);
    }
    ((bf16x8*)wsw)[id] = v;
  } else if (blk < 360) {
    int id = (blk - 320) * 256 + threadIdx.x;    // 8192 + 2048 = 10240
    if (id < VOCABSZ * EMBD) {
      embw[id] = tobf(emb[id]);
    } else {
      int r = id - VOCABSZ * EMBD;
      if (r < 2048) {
        int d = r >> 10, n = r & 1023;
        int g = (n & 3) * 256 + (n >> 2);
        biasg[r] = d ? (bihb[g] + bhhb[g]) : (bihf[g] + bhhf[g]);
      }
    }
  } else {  // blk == 360: length-bucket sort, 256 threads (bin order arbitrary -- OK)
    int tid = threadIdx.x;
    if (tid < 16) { hist[tid] = 0; cnt[tid] = 0; }
    __syncthreads();
    for (int i = tid; i < N_WORDS; i += 256)
      atomicAdd(&hist[lengths[i] - 1], 1);
    __syncthreads();
    if (tid == 0) {
      int s = 0;
      for (int b = 0; b < 16; ++b) { base[b] = s; s += hist[b]; }
    }
    __syncthreads();
    for (int i = tid; i < N_WORDS; i += 256) {
      int b = lengths[i] - 1;
      int p = base[b] + atomicAdd(&cnt[b], 1);
      sorted[p] = i;
    }
  }
}

// ---------------- main fused BiLSTM kernel ----------------
// R9 structural change vs R8: weight prefetch DISTANCE-3 in HALF-TILE units.
// Each tile's 10-kk weight block splits into lo/hi 5-kk halves; four rotating
// half-buffers H0..H3 (4x20 = 80 VGPRs, SAME cost as R8's wA/wB ping-pong).
// Issue slot j feeds consume slot j+3 -> cover = loMFMA + hiMFMA+epi + loMFMA
// (~370-500 cyc) vs R8's single-tile cover (~320). Rotation period = 2 tiles
// -> statically unrolled pair loop, all buffer names static (rule #20).
// Compiler's counted vmcnt on reg-dest global loads does the T4 work (R8-proven).
// acc = aL/aH per ct (4 independent MFMA chains), summed in epilogue.
__global__ __launch_bounds__(256, 2) void lstm_main(
    const int* __restrict__ char_ids, const int* __restrict__ lengths,
    const short* __restrict__ wsw, const short* __restrict__ embw,
    const float* __restrict__ biasg, const int* __restrict__ sorted,
    float* __restrict__ out) {
  __shared__ __align__(16) short A[M_TILE * AROW];   // [word][ h(256) | x(64) | pad ] 21 KB
  __shared__ __align__(16) int   charl[M_TILE * 16]; // 2 KB
  __shared__ __align__(16) float biasl[GATES];       // 4 KB
  __shared__ __align__(8)  f32x2 c4[4 * 16 * 64];    // [wv][rt][lane] cell state, 32 KB
  __shared__ int lenl[M_TILE];
  __shared__ int swl[M_TILE];

  const int tid  = threadIdx.x;
  const int lane = tid & 63;
  const int wv   = tid >> 6;            // 0..3
  const int quad = lane >> 4;
  const int colc = lane & 15;
  const int pb   = blockIdx.x;
  const int dir  = pb & 1;
  const int qb   = pb >> 1;
  const int tile = (qb & 1) ? (511 - (qb >> 1)) : (qb >> 1);

  if (tid < M_TILE) {
    int sw = sorted[tile * M_TILE + tid];
    swl[tid]  = sw;
    lenl[tid] = lengths[sw];
  }
  ((f32x4*)biasl)[tid] = ((const f32x4*)(biasg + dir * GATES))[tid];
  for (int i = tid; i < M_TILE * AROW / 2; i += 256) ((int*)A)[i] = 0;     // h=0 init
  for (int i = tid; i < 4 * 16 * 64; i += 256) c4[i] = (f32x2){0.f, 0.f};
  __syncthreads();

  if (tid < 128) { // char ids for the tile (via sorted ids): 32 words x 16
    int w = tid >> 2, ch = tid & 3;
    ((i32x4*)charl)[tid] = ((const i32x4*)(char_ids + swl[w] * 16))[ch];
  }
  int Lmax = lenl[lane & 31];
  for (int o = 32; o; o >>= 1) { int v = __shfl_xor(Lmax, o, 64); Lmax = Lmax > v ? Lmax : v; }
  __syncthreads();  // charl ready

  // stage x for timestep tt into A cols [256,320): wave w covers words 8w..8w+7
  auto gather_x = [&](int tt) {
    int wl = wv * 8 + (lane >> 3);
    int part = lane & 7;
    int lw = lenl[wl];
    int pos = (dir == 0) ? tt : (lw - 1 - tt);
    pos = pos < 0 ? 0 : (pos > 15 ? 15 : pos);
    int cid = charl[wl * 16 + pos];
    bf16x8 e = *(const bf16x8*)(embw + cid * EMBD + part * 8);
    *(bf16x8*)(A + wl * AROW + HID + part * 8) = e;
  };
  gather_x(0);

  // step-invariant lane constants (word dimension, per col-tile ct)
  int lenw[2], hadrb[2], oadr[2];
#pragma unroll
  for (int ct = 0; ct < 2; ++ct) {
    int wl = ct * 16 + colc;
    lenw[ct]  = lenl[wl];
    hadrb[ct] = wl * AROW + 64 * wv + quad;                  // + 4*rt : bf16 h slot in A
    oadr[ct]  = swl[wl] * 512 + dir * 256 + 64 * wv + quad;  // + 4*rt : fp32 out slot
  }
  const short* wp = wsw + ((size_t)dir * 64 + wv * 16) * 10 * 64 * 8 + lane * 8;
  f32x2* cptr = c4 + wv * (16 * 64) + lane;   // + rt*64

  __syncthreads();  // x / zeros visible

  // four rotating half-tile weight buffers (half j lives in H[j%4])
  bf16x8 H0[5], H1[5], H2[5], H3[5];
  auto ldh = [&](bf16x8 (&H)[5], int rt, int kb) {
#pragma unroll
    for (int k = 0; k < 5; ++k) H[k] = *(const bf16x8*)(wp + (rt * 10 + kb + k) * 512);
  };
  // prologue: halves 0,1,2 (tile0 lo, tile0 hi, tile1 lo) in flight
  ldh(H0, 0, 0); ldh(H1, 0, 5); ldh(H2, 1, 0);

#pragma unroll 1
  for (int t = 0; t < Lmax; ++t) {
    bf16x8 hx[2][10];  // B fragments: lane = B[k = kk*32 + quad*8 + j][n = ct*16 + colc]
#pragma unroll
    for (int ct = 0; ct < 2; ++ct)
#pragma unroll
      for (int kk = 0; kk < 10; ++kk)
        hx[ct][kk] = *(const bf16x8*)(A + (ct * 16 + colc) * AROW + kk * 32 + quad * 8);

    __syncthreads();  // all waves snapshotted A -> safe to overwrite h/x below

    auto mfma_half = [&](bf16x8 (&H)[5], f32x4 (&a)[2], const int kb) {
#pragma unroll
      for (int k = 0; k < 5; ++k)
#pragma unroll
        for (int ct = 0; ct < 2; ++ct)
          a[ct] = __builtin_amdgcn_mfma_f32_16x16x32_bf16(H[k], hx[ct][kb + k], a[ct], 0, 0, 0);
    };
    auto epi = [&](int rt, f32x4 (&aL)[2], f32x4 (&aH)[2]) {
      f32x2 co2 = cptr[rt * 64];                 // LDS c, covered by the MFMA block
      f32x2 cnew;
#pragma unroll
      for (int ct = 0; ct < 2; ++ct) {
        f32x4 acc = aL[ct] + aH[ct];
        // lane-private epilogue: regs = i,f,g,o of (unit 64wv+4rt+quad, word ct*16+colc)
        // always-write: masked words' h/c are don't-care (bounded, never output)
        float ig = fsig(acc[0]);
        float fg = fsig(acc[1]);
        float gg = ftanhf(acc[2]);
        float og = fsig(acc[3]);
        float c2 = fg * co2[ct] + ig * gg;
        float h2 = og * ftanhf(c2);
        cnew[ct] = c2;
        A[hadrb[ct] + 4 * rt] = tobf(h2);
        if (t == lenw[ct] - 1) out[oadr[ct] + 4 * rt] = h2;  // final h in fp32
      }
      cptr[rt * 64] = cnew;   // one ds_write_b64 (own slice, no hazard)
    };

#pragma unroll 1
    for (int p = 0; p < 8; ++p) {     // tile pairs; 4 consume-slots + 4 issue-slots
      const int rt0 = 2 * p, rt1 = 2 * p + 1;
      const int rn0 = (2 * p + 2) & 15, rn1 = (2 * p + 3) & 15;
      f32x4 aL[2], aH[2];
      // ---- tile rt0 ----
      {
        f32x4 b4 = *(const f32x4*)(biasl + 256 * wv + 16 * rt0 + 4 * quad);
        aL[0] = b4; aL[1] = b4;
        aH[0] = (f32x4){0.f, 0.f, 0.f, 0.f}; aH[1] = aH[0];
      }
      ldh(H3, rt1, 5);            // slot0 issue: half rt1-hi (consumed slot3)
      mfma_half(H0, aL, 0);       // slot0 consume: rt0-lo
      ldh(H0, rn0, 0);            // slot1 issue: next pair rt0'-lo
      mfma_half(H1, aH, 5);       // slot1 consume: rt0-hi
      epi(rt0, aL, aH);
      // ---- tile rt1 ----
      {
        f32x4 b4 = *(const f32x4*)(biasl + 256 * wv + 16 * rt1 + 4 * quad);
        aL[0] = b4; aL[1] = b4;
        aH[0] = (f32x4){0.f, 0.f, 0.f, 0.f}; aH[1] = aH[0];
      }
      ldh(H1, rn0, 5);            // slot2 issue: rt0'-hi
      mfma_half(H2, aL, 0);       // slot2 consume: rt1-lo
      ldh(H2, rn1, 0);            // slot3 issue: rt1'-lo
      mfma_half(H3, aH, 5);       // slot3 consume: rt1-hi
      epi(rt1, aL, aH);
    }
    // p=7 issued halves for next step's tiles 0/1 (rn0=0, rn1=1) -> cross-step
    // prefetch; the barrier's vmcnt drain just makes them land early. Dead-step
    // issues after t=Lmax-1 are in-bounds ((..)&15) and harmless.

    gather_x(t + 1);   // x for next step (clamped; dead steps are masked)
    __syncthreads();   // h/x writes visible before next step's reads
  }
}

// ---------------- launch ----------------
extern "C" void kernel_launch(void* const* d_in, const int* in_sizes, int n_in,
                              void* d_out, int out_size, void* d_ws, size_t ws_size,
                              hipStream_t stream) {
  const int*   char_ids = (const int*)d_in[0];
  const int*   lengths  = (const int*)d_in[1];
  const float* emb      = (const float*)d_in[2];
  const float* Wihf     = (const float*)d_in[3];
  const float* Whhf     = (const float*)d_in[4];
  const float* bihf     = (const float*)d_in[5];
  const float* bhhf     = (const float*)d_in[6];
  const float* Wihb     = (const float*)d_in[7];
  const float* Whhb     = (const float*)d_in[8];
  const float* bihb     = (const float*)d_in[9];
  const float* bhhb     = (const float*)d_in[10];

  char* ws = (char*)d_ws;
  short* wsw   = (short*)(ws + OFF_WSW);
  short* embw  = (short*)(ws + OFF_EMB);
  float* biasg = (float*)(ws + OFF_BIAS);
  int*   sortd = (int*)(ws + OFF_SORT);

  prep_all<<<361, 256, 0, stream>>>(Wihf, Whhf, Wihb, Whhb, emb,
                                    bihf, bhhf, bihb, bhhb, lengths,
                                    wsw, embw, biasg, sortd);
  lstm_main<<<1024, 256, 0, stream>>>(char_ids, lengths, wsw, embw, biasg, sortd,
                                      (float*)d_out);
}